// Round 16
// baseline (254.603 us; speedup 1.0000x reference)
//
#include <hip/hip_runtime.h>
#include <hip/hip_fp16.h>

#define NSENS 4
#define NB    64
#define LIN   2048
#define C1N   32
#define LP1   512
#define C2N   64
#define SEQ   256
#define DM    64

typedef _Float16 f16x4 __attribute__((ext_vector_type(4)));
typedef _Float16 f16x8 __attribute__((ext_vector_type(8)));
typedef float    f32x4 __attribute__((ext_vector_type(4)));

#define MFMA16(A,B,C) __builtin_amdgcn_mfma_f32_16x16x16f16((A),(B),(C),0,0,0)
#define MFMA32(A,B,C) __builtin_amdgcn_mfma_f32_16x16x32_f16((A),(B),(C),0,0,0)

__device__ __forceinline__ float fast_exp2(float x) {
#if __has_builtin(__builtin_amdgcn_exp2f)
  return __builtin_amdgcn_exp2f(x);
#else
  return exp2f(x);
#endif
}

// swizzled LDS addressing: 16B-chunk XOR by (row&7)<<4
__device__ __forceinline__ char* swp(char* base, int row, int stride, int byteoff) {
  return base + row*stride + ((byteoff & ~15) ^ ((row & 7) << 4)) + (byteoff & 15);
}
__device__ __forceinline__ float sr_h(char* base, int row, int stride, int col) {
  return (float)*(const _Float16*)swp(base, row, stride, col*2);
}
__device__ __forceinline__ uint2 pack4u(float a, float b, float cc, float d) {
  __half2 h0 = __floats2half2_rn(a, b), h1 = __floats2half2_rn(cc, d);
  uint2 u; u.x = *(unsigned*)&h0; u.y = *(unsigned*)&h1; return u;
}

// ---------------- weight pack: fp32 -> fp16, 64 blocks ----------------
__global__ __launch_bounds__(256) void wprep_kernel(
    const float* __restrict__ wqkv, const float* __restrict__ wo,
    const float* __restrict__ fw1,  const float* __restrict__ fw2,
    unsigned short* __restrict__ w16)
{
  const int wi = blockIdx.x >> 3, chunk = blockIdx.x & 7;
  unsigned short* dst = w16 + (size_t)wi*49152;
  const float* s0 = wqkv + (size_t)wi*12288;
  const float* s1 = wo   + (size_t)wi*4096;
  const float* s2 = fw1  + (size_t)wi*16384;
  const float* s3 = fw2  + (size_t)wi*16384;
  const int lo = chunk*6144, hi = lo + 6144;
  for (int i = lo + threadIdx.x; i < hi; i += 256) {
    float v;
    if (i < 12288)      v = s0[i];
    else if (i < 16384) v = s1[i - 12288];
    else if (i < 32768) v = s2[i - 16384];
    else                v = s3[i - 32768];
    __half h = __float2half_rn(v);
    dst[i] = *(unsigned short*)&h;
  }
}

// ---------------- fused conv + transformer kernel: 1024 threads = 16 waves ----------------
// LDS map: xs[256][64]f16 @0 | Qb @32K | Kb @64K | Vt[64][256] @96K | red @128K
// conv prologue overlays: h1t[514][32]f16 @32768, w2hT[3][64][32]f16 @65664
__global__ __launch_bounds__(1024, 1) void tx_kernel(
  const float* __restrict__ sens,
  const float* __restrict__ c1w, const float* __restrict__ c1b,
  const float* __restrict__ bn1g, const float* __restrict__ bn1b,
  const float* __restrict__ c2w, const float* __restrict__ c2b,
  const float* __restrict__ bn2g, const float* __restrict__ bn2b,
  float* __restrict__ nf,
  const unsigned short* __restrict__ w16,
  const float* __restrict__ bqkv, const float* __restrict__ bo,
  const float* __restrict__ ln1g, const float* __restrict__ ln1b,
  const float* __restrict__ fb1,  const float* __restrict__ fb2,
  const float* __restrict__ ln2g, const float* __restrict__ ln2b)
{
  __shared__ char smem[132096];
  char* xs = smem;
  char* Qb = smem + 32768;
  char* Kb = smem + 65536;
  char* Vt = smem + 98304;
  float* red = (float*)(smem + 131072);

  const int bid = blockIdx.x;
  const int s = bid >> 6, b = bid & 63;
  const int t = threadIdx.x;
  const int l = t & 63, w = t >> 6;
  const int g = l >> 4, c = l & 15;
  const int m0 = w * 16;
  const float qs = 0.35355339059327373f * 1.4426950408889634f; // 1/sqrt(8)*log2(e)

  // ================= conv prologue (MFMA conv2) =================
  {
    __half* h1t  = (__half*)(smem + 32768);    // [514][32]
    __half* w2hT = (__half*)(smem + 65664);    // [3][64][32]

    for (int i = t; i < 3*64*32; i += 1024) {
      const int ci = i & 31; const int rem = i >> 5; const int co = rem & 63; const int k = rem >> 6;
      w2hT[i] = __float2half_rn(c2w[((s*C2N + co)*C1N + ci)*3 + k]);
    }
    if (t < 32) { h1t[t] = __float2half(0.f); h1t[513*32 + t] = __float2half(0.f); }

    const float* xg = sens + (size_t)(s*NB + b)*LIN;
    const float bnr = rsqrtf(1.0f + 1e-5f);
    {
      const int ch = t & 31;
      const int l0 = t >> 5;
      const float w0 = c1w[(s*C1N + ch)*5 + 0];
      const float w1 = c1w[(s*C1N + ch)*5 + 1];
      const float w2 = c1w[(s*C1N + ch)*5 + 2];
      const float w3 = c1w[(s*C1N + ch)*5 + 3];
      const float w4 = c1w[(s*C1N + ch)*5 + 4];
      const float cb = c1b[s*C1N + ch];
      const float sc = bn1g[s*C1N + ch]*bnr;
      const float bt = bn1b[s*C1N + ch];
      for (int ll = l0; ll < LP1; ll += 32) {
        const int base = 4*ll;
        float xm2 = (base-2 >= 0) ? xg[base-2] : 0.f;
        float xm1 = (base-1 >= 0) ? xg[base-1] : 0.f;
        float x0v = xg[base+0];
        float x1v = xg[base+1];
        float x2v = xg[base+2];
        float x3v = xg[base+3];
        float x4v = (base+4 < LIN) ? xg[base+4] : 0.f;
        float y0 = w0*xm2 + w1*xm1 + w2*x0v + w3*x1v + w4*x2v;
        float y1 = w0*x0v + w1*x1v + w2*x2v + w3*x3v + w4*x4v;
        y0 = (y0 + cb)*sc + bt;
        y1 = (y1 + cb)*sc + bt;
        h1t[(ll+1)*32 + ch] = __float2half(fmaxf(fmaxf(y0, y1), 0.f));
      }
    }
    __syncthreads();
    {
      const int p0a = m0*2, p0b = m0*2 + 16;
      f16x8 aA[3], aB[3];
      #pragma unroll
      for (int k = 0; k < 3; ++k) {
        aA[k] = *(const f16x8*)&h1t[(p0a + c + k)*32 + 8*g];
        aB[k] = *(const f16x8*)&h1t[(p0b + c + k)*32 + 8*g];
      }
      #pragma unroll
      for (int ct = 0; ct < 4; ++ct) {
        f32x4 dA = {0.f,0.f,0.f,0.f}, dB = {0.f,0.f,0.f,0.f};
        #pragma unroll
        for (int k = 0; k < 3; ++k) {
          f16x8 bw = *(const f16x8*)&w2hT[(k*64 + ct*16 + c)*32 + 8*g];
          dA = MFMA32(aA[k], bw, dA);
          dB = MFMA32(aB[k], bw, dB);
        }
        const int d = ct*16 + c;
        const float cb2 = c2b[s*C2N + d];
        const float sc2 = bn2g[s*C2N + d]*bnr;
        const float bt2 = bn2b[s*C2N + d];
        const float efac = __expf(-0.14391156463f*(float)(d & ~1));
        float v[4];
        v[0] = fmaxf(fmaxf((dA[0]+cb2)*sc2+bt2, (dA[1]+cb2)*sc2+bt2), 0.f);
        v[1] = fmaxf(fmaxf((dA[2]+cb2)*sc2+bt2, (dA[3]+cb2)*sc2+bt2), 0.f);
        v[2] = fmaxf(fmaxf((dB[0]+cb2)*sc2+bt2, (dB[1]+cb2)*sc2+bt2), 0.f);
        v[3] = fmaxf(fmaxf((dB[2]+cb2)*sc2+bt2, (dB[3]+cb2)*sc2+bt2), 0.f);
        const int rr[4] = { m0+2*g, m0+2*g+1, m0+8+2*g, m0+8+2*g+1 };
        #pragma unroll
        for (int i = 0; i < 4; ++i) {
          const float ang = (float)rr[i] * efac;
          const float pe = (d & 1) ? cosf(ang) : sinf(ang);
          *(_Float16*)swp(xs, rr[i], 128, d*2) = (_Float16)(v[i] + pe);
        }
      }
    }
  }
  __syncthreads();

  // ================= transformer layers =================
  for (int layer = 0; layer < 2; ++layer) {
    const int wi = s*2 + layer;
    const unsigned short* wq = w16 + (size_t)wi*49152;
    const unsigned short* wo = wq + 12288;
    const unsigned short* w1 = wq + 16384;
    const unsigned short* w2 = wq + 32768;
    const float* Bq  = bqkv + wi*192;
    const float* Bo  = bo   + wi*64;
    const float* G1  = ln1g + wi*64; const float* B1 = ln1b + wi*64;
    const float* Bf1 = fb1  + wi*256; const float* Bf2 = fb2 + wi*64;
    const float* G2  = ln2g + wi*64; const float* B2 = ln2b + wi*64;

    // ======== QKV projections ========
    {
      f16x8 xf0 = *(const f16x8*)swp(xs, m0+c, 128, 0  + g*16);
      f16x8 xf1 = *(const f16x8*)swp(xs, m0+c, 128, 64 + g*16);
      #pragma unroll
      for (int nt = 0; nt < 4; ++nt) {
        const int row = 64 + nt*16 + c;
        f16x8 w0f = *(const f16x8*)(wq + row*64 + 8*g);
        f16x8 w1f = *(const f16x8*)(wq + row*64 + 32 + 8*g);
        f32x4 d = {0.f,0.f,0.f,0.f};
        d = MFMA32(w0f, xf0, d); d = MFMA32(w1f, xf1, d);
        float4 b4 = *(const float4*)(Bq + 64 + nt*16 + 4*g);
        *(uint2*)swp(Kb, m0+c, 128, nt*32 + 8*g) =
            pack4u(d[0]+b4.x, d[1]+b4.y, d[2]+b4.z, d[3]+b4.w);
      }
      #pragma unroll
      for (int nt = 0; nt < 4; ++nt) {
        const int row = nt*16 + c;
        f16x8 w0f = *(const f16x8*)(wq + row*64 + 8*g);
        f16x8 w1f = *(const f16x8*)(wq + row*64 + 32 + 8*g);
        f32x4 d = {0.f,0.f,0.f,0.f};
        d = MFMA32(w0f, xf0, d); d = MFMA32(w1f, xf1, d);
        float4 b4 = *(const float4*)(Bq + nt*16 + 4*g);
        *(uint2*)swp(Qb, m0+c, 128, nt*32 + 8*g) =
            pack4u((d[0]+b4.x)*qs, (d[1]+b4.y)*qs, (d[2]+b4.z)*qs, (d[3]+b4.w)*qs);
      }
      #pragma unroll
      for (int nt = 0; nt < 4; ++nt) {
        const int row = 128 + nt*16 + c;
        f16x8 w0f = *(const f16x8*)(wq + row*64 + 8*g);
        f16x8 w1f = *(const f16x8*)(wq + row*64 + 32 + 8*g);
        f32x4 d = {0.f,0.f,0.f,0.f};
        d = MFMA32(xf0, w0f, d); d = MFMA32(xf1, w1f, d);
        const float bias = Bq[128 + nt*16 + c];
        *(uint2*)swp(Vt, nt*16+c, 512, 32*w + 8*g) =
            pack4u(d[0]+bias, d[1]+bias, d[2]+bias, d[3]+bias);
      }
    }
    __syncthreads();   // (a) Q/K/Vt visible to all

    // ======== attention: paired heads, 4 independent accumulator chains ========
    #pragma unroll
    for (int tp = 0; tp < 4; ++tp) {
      const int h0 = 2*tp, h1 = 2*tp + 1;
      f16x4 qb0 = {0,0,0,0}, qb1 = {0,0,0,0};
      if (g < 2) {
        qb0 = *(const f16x4*)swp(Qb, m0+c, 128, 16*h0 + 8*g);
        qb1 = *(const f16x4*)swp(Qb, m0+c, 128, 16*h1 + 8*g);
      }
      f32x4 o0A = {0.f,0.f,0.f,0.f}, o0B = {0.f,0.f,0.f,0.f};
      f32x4 o1A = {0.f,0.f,0.f,0.f}, o1B = {0.f,0.f,0.f,0.f};
      #pragma unroll
      for (int jt = 0; jt < 16; ++jt) {
        f16x4 ka0 = *(const f16x4*)swp(Kb, jt*16+c, 128, (16*h0 + 8*g) & 127);
        f16x4 ka1 = *(const f16x4*)swp(Kb, jt*16+c, 128, (16*h1 + 8*g) & 127);
        f32x4 st0 = {0.f,0.f,0.f,0.f}; st0 = MFMA16(ka0, qb0, st0);
        f32x4 st1 = {0.f,0.f,0.f,0.f}; st1 = MFMA16(ka1, qb1, st1);
        uint2 pu0 = pack4u(fast_exp2(st0[0]), fast_exp2(st0[1]),
                           fast_exp2(st0[2]), fast_exp2(st0[3]));
        uint2 pu1 = pack4u(fast_exp2(st1[0]), fast_exp2(st1[1]),
                           fast_exp2(st1[2]), fast_exp2(st1[3]));
        f16x4 pb0 = *(f16x4*)&pu0;
        f16x4 pb1 = *(f16x4*)&pu1;
        f16x4 va0, va1;
        if (c < 8) {
          va0 = *(const f16x4*)swp(Vt, 8*h0+c, 512, jt*32 + (g>>1)*16 + (g&1)*8);
          va1 = *(const f16x4*)swp(Vt, 8*h1+c, 512, jt*32 + (g>>1)*16 + (g&1)*8);
        } else {
          va0[0]=(_Float16)1.f; va0[1]=(_Float16)1.f; va0[2]=(_Float16)1.f; va0[3]=(_Float16)1.f;
          va1 = va0;
        }
        if (jt & 1) { o0B = MFMA16(va0, pb0, o0B); o1B = MFMA16(va1, pb1, o1B); }
        else        { o0A = MFMA16(va0, pb0, o0A); o1A = MFMA16(va1, pb1, o1A); }
      }
      f32x4 o0, o1;
      o0[0]=o0A[0]+o0B[0]; o0[1]=o0A[1]+o0B[1]; o0[2]=o0A[2]+o0B[2]; o0[3]=o0A[3]+o0B[3];
      o1[0]=o1A[0]+o1B[0]; o1[1]=o1A[1]+o1B[1]; o1[2]=o1A[2]+o1B[2]; o1[3]=o1A[3]+o1B[3];
      const float den0 = __shfl(o0[0], 32 + c, 64);
      const float den1 = __shfl(o1[0], 32 + c, 64);
      const float rinv0 = 1.0f / den0;
      const float rinv1 = 1.0f / den1;
      if (g < 2) {
        *(uint2*)swp(Qb, m0+c, 128, 16*h0 + 8*g) =
            pack4u(o0[0]*rinv0, o0[1]*rinv0, o0[2]*rinv0, o0[3]*rinv0);
        *(uint2*)swp(Qb, m0+c, 128, 16*h1 + 8*g) =
            pack4u(o1[0]*rinv1, o1[1]*rinv1, o1[2]*rinv1, o1[3]*rinv1);
      }
    }
    __syncthreads();   // (b) cross-wave reads complete

    // ======== O-projection + residual + LN1 ========
    {
      f16x8 ab0 = *(const f16x8*)swp(Qb, m0+c, 128, 0  + g*16);
      f16x8 ab1 = *(const f16x8*)swp(Qb, m0+c, 128, 64 + g*16);
      float vals[4][4];
      #pragma unroll
      for (int nt = 0; nt < 4; ++nt) {
        f16x8 w0f = *(const f16x8*)(wo + (nt*16+c)*64 + 8*g);
        f16x8 w1f = *(const f16x8*)(wo + (nt*16+c)*64 + 32 + 8*g);
        f32x4 d = {0.f,0.f,0.f,0.f};
        d = MFMA32(w0f, ab0, d); d = MFMA32(w1f, ab1, d);
        float4 b4 = *(const float4*)(Bo + nt*16 + 4*g);
        uint2 rr = *(uint2*)swp(xs, m0+c, 128, nt*32 + 8*g);
        float2 r0 = __half22float2(*(__half2*)&rr.x);
        float2 r1 = __half22float2(*(__half2*)&rr.y);
        vals[nt][0] = d[0] + b4.x + r0.x;
        vals[nt][1] = d[1] + b4.y + r0.y;
        vals[nt][2] = d[2] + b4.z + r1.x;
        vals[nt][3] = d[3] + b4.w + r1.y;
      }
      float p1 = 0.f, p2 = 0.f;
      #pragma unroll
      for (int nt = 0; nt < 4; ++nt)
        #pragma unroll
        for (int i = 0; i < 4; ++i) { p1 += vals[nt][i]; p2 = fmaf(vals[nt][i], vals[nt][i], p2); }
      p1 += __shfl_xor(p1, 16, 64); p1 += __shfl_xor(p1, 32, 64);
      p2 += __shfl_xor(p2, 16, 64); p2 += __shfl_xor(p2, 32, 64);
      const float mean = p1*(1.0f/64.0f);
      const float rstd = rsqrtf(p2*(1.0f/64.0f) - mean*mean + 1e-5f);
      #pragma unroll
      for (int nt = 0; nt < 4; ++nt) {
        float4 g4 = *(const float4*)(G1 + nt*16 + 4*g);
        float4 b4 = *(const float4*)(B1 + nt*16 + 4*g);
        *(uint2*)swp(xs, m0+c, 128, nt*32 + 8*g) =
            pack4u((vals[nt][0]-mean)*rstd*g4.x + b4.x,
                   (vals[nt][1]-mean)*rstd*g4.y + b4.y,
                   (vals[nt][2]-mean)*rstd*g4.z + b4.z,
                   (vals[nt][3]-mean)*rstd*g4.w + b4.w);
      }
    }

    // ======== FF fused ========
    {
      f16x8 xb0 = *(const f16x8*)swp(xs, m0+c, 128, 0  + g*16);
      f16x8 xb1 = *(const f16x8*)swp(xs, m0+c, 128, 64 + g*16);
      f32x4 o2[4];
      #pragma unroll
      for (int nt2 = 0; nt2 < 4; ++nt2) { o2[nt2][0]=0.f; o2[nt2][1]=0.f; o2[nt2][2]=0.f; o2[nt2][3]=0.f; }
      #pragma unroll
      for (int ht = 0; ht < 16; ++ht) {
        f16x8 w0f = *(const f16x8*)(w1 + (ht*16+c)*64 + 8*g);
        f16x8 w1f = *(const f16x8*)(w1 + (ht*16+c)*64 + 32 + 8*g);
        f32x4 d = {0.f,0.f,0.f,0.f};
        d = MFMA32(w0f, xb0, d); d = MFMA32(w1f, xb1, d);
        float4 bf4 = *(const float4*)(Bf1 + ht*16 + 4*g);
        float h0 = d[0] + bf4.x, h1 = d[1] + bf4.y, h2 = d[2] + bf4.z, h3 = d[3] + bf4.w;
        h0 = 0.5f*h0*(1.0f + erff(h0*0.70710678118654752f));
        h1 = 0.5f*h1*(1.0f + erff(h1*0.70710678118654752f));
        h2 = 0.5f*h2*(1.0f + erff(h2*0.70710678118654752f));
        h3 = 0.5f*h3*(1.0f + erff(h3*0.70710678118654752f));
        uint2 pu = pack4u(h0, h1, h2, h3);
        f16x4 pf = *(f16x4*)&pu;
        #pragma unroll
        for (int nt2 = 0; nt2 < 4; ++nt2) {
          f16x4 a2 = *(const f16x4*)(w2 + (nt2*16+c)*256 + ht*16 + 4*g);
          o2[nt2] = MFMA16(a2, pf, o2[nt2]);
        }
      }
      float vals[4][4];
      #pragma unroll
      for (int nt2 = 0; nt2 < 4; ++nt2) {
        float4 b4 = *(const float4*)(Bf2 + nt2*16 + 4*g);
        uint2 rr = *(uint2*)swp(xs, m0+c, 128, nt2*32 + 8*g);
        float2 r0 = __half22float2(*(__half2*)&rr.x);
        float2 r1 = __half22float2(*(__half2*)&rr.y);
        vals[nt2][0] = o2[nt2][0] + b4.x + r0.x;
        vals[nt2][1] = o2[nt2][1] + b4.y + r0.y;
        vals[nt2][2] = o2[nt2][2] + b4.z + r1.x;
        vals[nt2][3] = o2[nt2][3] + b4.w + r1.y;
      }
      float p1 = 0.f, p2 = 0.f;
      #pragma unroll
      for (int nt2 = 0; nt2 < 4; ++nt2)
        #pragma unroll
        for (int i = 0; i < 4; ++i) { p1 += vals[nt2][i]; p2 = fmaf(vals[nt2][i], vals[nt2][i], p2); }
      p1 += __shfl_xor(p1, 16, 64); p1 += __shfl_xor(p1, 32, 64);
      p2 += __shfl_xor(p2, 16, 64); p2 += __shfl_xor(p2, 32, 64);
      const float mean = p1*(1.0f/64.0f);
      const float rstd = rsqrtf(p2*(1.0f/64.0f) - mean*mean + 1e-5f);
      #pragma unroll
      for (int nt2 = 0; nt2 < 4; ++nt2) {
        float4 g4 = *(const float4*)(G2 + nt2*16 + 4*g);
        float4 b4 = *(const float4*)(B2 + nt2*16 + 4*g);
        *(uint2*)swp(xs, m0+c, 128, nt2*32 + 8*g) =
            pack4u((vals[nt2][0]-mean)*rstd*g4.x + b4.x,
                   (vals[nt2][1]-mean)*rstd*g4.y + b4.y,
                   (vals[nt2][2]-mean)*rstd*g4.z + b4.z,
                   (vals[nt2][3]-mean)*rstd*g4.w + b4.w);
      }
    }
  }

  // ---- mean over sequence -> nf ----
  __syncthreads();
  if (t < 256) {
    const int d = t & 63, qu = t >> 6;
    float sm = 0.f;
    for (int rr = qu*64; rr < qu*64 + 64; ++rr) sm += sr_h(xs, rr, 128, d);
    red[qu*64 + d] = sm;
  }
  __syncthreads();
  if (t < 64) {
    float sm = red[t] + red[64+t] + red[128+t] + red[192+t];
    nf[((size_t)b*4 + s)*64 + t] = sm * (1.0f/256.0f);
  }
}

// ------------------------- graph head kernel (unchanged) -------------------------
__global__ __launch_bounds__(128) void head_kernel(
  const float* __restrict__ nf,
  const float* __restrict__ ws_w, const float* __restrict__ ws_b,
  const float* __restrict__ b_s,  const float* __restrict__ lambda_init,
  const float* __restrict__ mc_w1, const float* __restrict__ mc_b1,
  const float* __restrict__ mc_w2, const float* __restrict__ mc_b2,
  const float* __restrict__ g1w, const float* __restrict__ g1b,
  const float* __restrict__ g2w, const float* __restrict__ g2b,
  const float* __restrict__ cw1, const float* __restrict__ cb1,
  const float* __restrict__ cw2, const float* __restrict__ cb2,
  float* __restrict__ out)
{
  const int b = blockIdx.x, t = threadIdx.x;
  __shared__ float nfb[256];
  __shared__ float meannf[64];
  __shared__ float fafb[8];
  __shared__ float z1[32];
  __shared__ float normM[16];
  __shared__ float rs[4];
  __shared__ float xw[512];
  __shared__ float hmat[512];
  __shared__ float hw[1024];
  __shared__ float gv[256];
  __shared__ float r1[128];

  for (int i = t; i < 256; i += 128) nfb[i] = nf[b*256 + i];
  __syncthreads();
  if (t < 8) {
    const int i = t & 3;
    const float* w = ws_w + (t >> 2)*64;
    float acc = 0.f;
    for (int c = 0; c < 64; ++c) acc = fmaf(nfb[i*64+c], w[c], acc);
    fafb[t] = acc;
  }
  if (t >= 64 && t < 128) {
    const int d = t - 64;
    meannf[d] = 0.25f*(nfb[d] + nfb[64+d] + nfb[128+d] + nfb[192+d]);
  }
  __syncthreads();
  if (t < 32) {
    float acc = mc_b1[t];
    const float* w = mc_w1 + t*64;
    for (int c = 0; c < 64; ++c) acc = fmaf(meannf[c], w[c], acc);
    z1[t] = fmaxf(acc, 0.f);
  }
  __syncthreads();
  if (t == 0) {
    float li = mc_b2[0];
    for (int k = 0; k < 32; ++k) li = fmaf(z1[k], mc_w2[k], li);
    const float lam = (1.0f/(1.0f + __expf(-li))) * lambda_init[0];
    const float AB[4][4] = {{1,1,0,0},{1,1,1,1},{0,1,1,1},{0,1,1,1}};
    const float add = ws_b[0] + b_s[0];
    float sM[4][4], deg[4];
    for (int i = 0; i < 4; ++i) {
      float d_ = 0.f;
      for (int j = 0; j < 4; ++j) {
        sM[i][j] = 1.0f/(1.0f + __expf(-(fafb[i] + fafb[4+j] + add)));
        d_ += sM[i][j];
      }
      deg[i] = d_;
    }
    float A[4][4], dinv[4];
    for (int i = 0; i < 4; ++i)
      for (int j = 0; j < 4; ++j) {
        const float a_ = sM[i][j] / (deg[j] + 1e-8f);
        const float sh = fmaxf(a_ * AB[i][j], 0.f);
        A[i][j] = lam*((i==j) ? 1.f : 0.f) + (1.0f - lam)*sh;
      }
    for (int j = 0; j < 4; ++j) {
      float d_ = 0.f;
      for (int i = 0; i < 4; ++i) d_ += A[i][j];
      dinv[j] = (d_ > 0.f) ? rsqrtf(d_) : 0.f;
    }
    for (int i = 0; i < 4; ++i) {
      float r_ = 0.f;
      for (int j = 0; j < 4; ++j) {
        const float n_ = dinv[i]*A[i][j]*dinv[j];
        normM[i*4+j] = n_;
        r_ += n_;
      }
      rs[i] = r_;
    }
  }
  __syncthreads();
  for (int idx = t; idx < 512; idx += 128) {
    const int i = idx >> 7, f = idx & 127;
    float acc = 0.f;
    for (int c = 0; c < 64; ++c) acc = fmaf(nfb[i*64+c], g1w[c*128 + f], acc);
    xw[idx] = acc;
  }
  __syncthreads();
  for (int idx = t; idx < 512; idx += 128) {
    const int j = idx >> 7, f = idx & 127;
    float acc = g1b[f];
    #pragma unroll
    for (int i = 0; i < 4; ++i) acc = fmaf(normM[i*4+j], xw[i*128+f], acc);
    hmat[j*128+f] = fmaxf(acc, 0.f);
  }
  __syncthreads();
  for (int idx = t; idx < 1024; idx += 128) {
    const int i = idx >> 8, f = idx & 255;
    float acc = 0.f;
    for (int c = 0; c < 128; ++c) acc = fmaf(hmat[i*128+c], g2w[c*256+f], acc);
    hw[idx] = acc;
  }
  __syncthreads();
  for (int f = t; f < 256; f += 128) {
    float acc = 0.f;
    #pragma unroll
    for (int i = 0; i < 4; ++i) acc = fmaf(rs[i], hw[i*256+f], acc);
    gv[f] = 0.25f*acc + g2b[f];
  }
  __syncthreads();
  if (t < 128) {
    float acc = cb1[t];
    for (int c = 0; c < 256; ++c) acc = fmaf(gv[c], cw1[c*128+t], acc);
    r1[t] = fmaxf(acc, 0.f);
  }
  __syncthreads();
  if (t < 5) {
    float acc = cb2[t];
    for (int k = 0; k < 128; ++k) acc = fmaf(r1[k], cw2[k*5 + t], acc);
    out[b*5 + t] = acc;
  }
}

// ------------------------- launch -------------------------
extern "C" void kernel_launch(void* const* d_in, const int* in_sizes, int n_in,
                              void* d_out, int out_size, void* d_ws, size_t ws_size,
                              hipStream_t stream) {
  (void)in_sizes; (void)n_in; (void)out_size; (void)ws_size;
  const float* sens   = (const float*)d_in[0];
  const float* c1w    = (const float*)d_in[1];
  const float* c1b    = (const float*)d_in[2];
  const float* bn1g   = (const float*)d_in[3];
  const float* bn1b   = (const float*)d_in[4];
  const float* c2w    = (const float*)d_in[5];
  const float* c2b    = (const float*)d_in[6];
  const float* bn2g   = (const float*)d_in[7];
  const float* bn2b   = (const float*)d_in[8];
  const float* wqkv   = (const float*)d_in[9];
  const float* bqkv   = (const float*)d_in[10];
  const float* wo     = (const float*)d_in[11];
  const float* bo     = (const float*)d_in[12];
  const float* ln1g   = (const float*)d_in[13];
  const float* ln1b   = (const float*)d_in[14];
  const float* fw1    = (const float*)d_in[15];
  const float* fb1    = (const float*)d_in[16];
  const float* fw2    = (const float*)d_in[17];
  const float* fb2    = (const float*)d_in[18];
  const float* ln2g   = (const float*)d_in[19];
  const float* ln2b   = (const float*)d_in[20];
  const float* ws_w   = (const float*)d_in[21];
  const float* ws_b   = (const float*)d_in[22];
  const float* b_s    = (const float*)d_in[23];
  const float* lam0   = (const float*)d_in[24];
  const float* mc_w1  = (const float*)d_in[25];
  const float* mc_b1  = (const float*)d_in[26];
  const float* mc_w2  = (const float*)d_in[27];
  const float* mc_b2  = (const float*)d_in[28];
  const float* g1w    = (const float*)d_in[29];
  const float* g1b    = (const float*)d_in[30];
  const float* g2w    = (const float*)d_in[31];
  const float* g2b    = (const float*)d_in[32];
  const float* cw1    = (const float*)d_in[33];
  const float* cb1    = (const float*)d_in[34];
  const float* cw2    = (const float*)d_in[35];
  const float* cb2    = (const float*)d_in[36];

  float*          nf  = (float*)d_ws;                                  // 64 KiB
  unsigned short* w16 = (unsigned short*)((char*)d_ws + 65536);        // 768 KiB

  wprep_kernel<<<64, 256, 0, stream>>>(wqkv, wo, fw1, fw2, w16);
  tx_kernel<<<NSENS*NB, 1024, 0, stream>>>(sens, c1w, c1b, bn1g, bn1b,
                                           c2w, c2b, bn2g, bn2b,
                                           nf, w16, bqkv, bo,
                                           ln1g, ln1b, fb1, fb2, ln2g, ln2b);
  head_kernel<<<NB, 128, 0, stream>>>(nf, ws_w, ws_b, b_s, lam0,
                                      mc_w1, mc_b1, mc_w2, mc_b2,
                                      g1w, g1b, g2w, g2b, cw1, cb1, cw2, cb2,
                                      (float*)d_out);
}

// Round 17
// 215.525 us; speedup vs baseline: 1.1813x; 1.1813x over previous
//
#include <hip/hip_runtime.h>
#include <hip/hip_fp16.h>

#define NSENS 4
#define NB    64
#define LIN   2048
#define C1N   32
#define LP1   512
#define C2N   64
#define SEQ   256
#define DM    64

typedef _Float16 f16x4 __attribute__((ext_vector_type(4)));
typedef _Float16 f16x8 __attribute__((ext_vector_type(8)));
typedef float    f32x4 __attribute__((ext_vector_type(4)));

#define MFMA16(A,B,C) __builtin_amdgcn_mfma_f32_16x16x16f16((A),(B),(C),0,0,0)
#define MFMA32(A,B,C) __builtin_amdgcn_mfma_f32_16x16x32_f16((A),(B),(C),0,0,0)

__device__ __forceinline__ float fast_exp2(float x) {
#if __has_builtin(__builtin_amdgcn_exp2f)
  return __builtin_amdgcn_exp2f(x);
#else
  return exp2f(x);
#endif
}

// swizzled LDS addressing: 16B-chunk XOR by (row&7)<<4
__device__ __forceinline__ char* swp(char* base, int row, int stride, int byteoff) {
  return base + row*stride + ((byteoff & ~15) ^ ((row & 7) << 4)) + (byteoff & 15);
}
__device__ __forceinline__ float sr_h(char* base, int row, int stride, int col) {
  return (float)*(const _Float16*)swp(base, row, stride, col*2);
}
__device__ __forceinline__ uint2 pack4u(float a, float b, float cc, float d) {
  __half2 h0 = __floats2half2_rn(a, b), h1 = __floats2half2_rn(cc, d);
  uint2 u; u.x = *(unsigned*)&h0; u.y = *(unsigned*)&h1; return u;
}

// ---------------- weight pack: fp32 -> fp16, 64 blocks ----------------
__global__ __launch_bounds__(256) void wprep_kernel(
    const float* __restrict__ wqkv, const float* __restrict__ wo,
    const float* __restrict__ fw1,  const float* __restrict__ fw2,
    unsigned short* __restrict__ w16)
{
  const int wi = blockIdx.x >> 3, chunk = blockIdx.x & 7;
  unsigned short* dst = w16 + (size_t)wi*49152;
  const float* s0 = wqkv + (size_t)wi*12288;
  const float* s1 = wo   + (size_t)wi*4096;
  const float* s2 = fw1  + (size_t)wi*16384;
  const float* s3 = fw2  + (size_t)wi*16384;
  const int lo = chunk*6144, hi = lo + 6144;
  for (int i = lo + threadIdx.x; i < hi; i += 256) {
    float v;
    if (i < 12288)      v = s0[i];
    else if (i < 16384) v = s1[i - 12288];
    else if (i < 32768) v = s2[i - 16384];
    else                v = s3[i - 32768];
    __half h = __float2half_rn(v);
    dst[i] = *(unsigned short*)&h;
  }
}

// ---------------- fused conv + transformer kernel: 1024 threads = 16 waves ----------------
// LDS map: xs[256][64]f16 @0 | Qb @32K | Kb @64K | Vt[64][256] @96K | red @128K
// conv prologue overlays: h1t[514][32]f16 @32768, w2hT[3][64][32]f16 @65664
__global__ __launch_bounds__(1024, 1) void tx_kernel(
  const float* __restrict__ sens,
  const float* __restrict__ c1w, const float* __restrict__ c1b,
  const float* __restrict__ bn1g, const float* __restrict__ bn1b,
  const float* __restrict__ c2w, const float* __restrict__ c2b,
  const float* __restrict__ bn2g, const float* __restrict__ bn2b,
  float* __restrict__ nf,
  const unsigned short* __restrict__ w16,
  const float* __restrict__ bqkv, const float* __restrict__ bo,
  const float* __restrict__ ln1g, const float* __restrict__ ln1b,
  const float* __restrict__ fb1,  const float* __restrict__ fb2,
  const float* __restrict__ ln2g, const float* __restrict__ ln2b)
{
  __shared__ char smem[132096];
  char* xs = smem;
  char* Qb = smem + 32768;
  char* Kb = smem + 65536;
  char* Vt = smem + 98304;
  float* red = (float*)(smem + 131072);

  const int bid = blockIdx.x;
  const int s = bid >> 6, b = bid & 63;
  const int t = threadIdx.x;
  const int l = t & 63, w = t >> 6;
  const int g = l >> 4, c = l & 15;
  const int m0 = w * 16;
  const float qs = 0.35355339059327373f * 1.4426950408889634f; // 1/sqrt(8)*log2(e)

  // ================= conv prologue (MFMA conv2) =================
  {
    __half* h1t  = (__half*)(smem + 32768);    // [514][32]
    __half* w2hT = (__half*)(smem + 65664);    // [3][64][32]

    for (int i = t; i < 3*64*32; i += 1024) {
      const int ci = i & 31; const int rem = i >> 5; const int co = rem & 63; const int k = rem >> 6;
      w2hT[i] = __float2half_rn(c2w[((s*C2N + co)*C1N + ci)*3 + k]);
    }
    if (t < 32) { h1t[t] = __float2half(0.f); h1t[513*32 + t] = __float2half(0.f); }

    const float* xg = sens + (size_t)(s*NB + b)*LIN;
    const float bnr = rsqrtf(1.0f + 1e-5f);
    {
      const int ch = t & 31;
      const int l0 = t >> 5;
      const float w0 = c1w[(s*C1N + ch)*5 + 0];
      const float w1 = c1w[(s*C1N + ch)*5 + 1];
      const float w2 = c1w[(s*C1N + ch)*5 + 2];
      const float w3 = c1w[(s*C1N + ch)*5 + 3];
      const float w4 = c1w[(s*C1N + ch)*5 + 4];
      const float cb = c1b[s*C1N + ch];
      const float sc = bn1g[s*C1N + ch]*bnr;
      const float bt = bn1b[s*C1N + ch];
      for (int ll = l0; ll < LP1; ll += 32) {
        const int base = 4*ll;
        float xm2 = (base-2 >= 0) ? xg[base-2] : 0.f;
        float xm1 = (base-1 >= 0) ? xg[base-1] : 0.f;
        float x0v = xg[base+0];
        float x1v = xg[base+1];
        float x2v = xg[base+2];
        float x3v = xg[base+3];
        float x4v = (base+4 < LIN) ? xg[base+4] : 0.f;
        float y0 = w0*xm2 + w1*xm1 + w2*x0v + w3*x1v + w4*x2v;
        float y1 = w0*x0v + w1*x1v + w2*x2v + w3*x3v + w4*x4v;
        y0 = (y0 + cb)*sc + bt;
        y1 = (y1 + cb)*sc + bt;
        h1t[(ll+1)*32 + ch] = __float2half(fmaxf(fmaxf(y0, y1), 0.f));
      }
    }
    __syncthreads();
    {
      const int p0a = m0*2, p0b = m0*2 + 16;
      f16x8 aA[3], aB[3];
      #pragma unroll
      for (int k = 0; k < 3; ++k) {
        aA[k] = *(const f16x8*)&h1t[(p0a + c + k)*32 + 8*g];
        aB[k] = *(const f16x8*)&h1t[(p0b + c + k)*32 + 8*g];
      }
      #pragma unroll
      for (int ct = 0; ct < 4; ++ct) {
        f32x4 dA = {0.f,0.f,0.f,0.f}, dB = {0.f,0.f,0.f,0.f};
        #pragma unroll
        for (int k = 0; k < 3; ++k) {
          f16x8 bw = *(const f16x8*)&w2hT[(k*64 + ct*16 + c)*32 + 8*g];
          dA = MFMA32(aA[k], bw, dA);
          dB = MFMA32(aB[k], bw, dB);
        }
        const int d = ct*16 + c;
        const float cb2 = c2b[s*C2N + d];
        const float sc2 = bn2g[s*C2N + d]*bnr;
        const float bt2 = bn2b[s*C2N + d];
        const float efac = __expf(-0.14391156463f*(float)(d & ~1));
        float v[4];
        v[0] = fmaxf(fmaxf((dA[0]+cb2)*sc2+bt2, (dA[1]+cb2)*sc2+bt2), 0.f);
        v[1] = fmaxf(fmaxf((dA[2]+cb2)*sc2+bt2, (dA[3]+cb2)*sc2+bt2), 0.f);
        v[2] = fmaxf(fmaxf((dB[0]+cb2)*sc2+bt2, (dB[1]+cb2)*sc2+bt2), 0.f);
        v[3] = fmaxf(fmaxf((dB[2]+cb2)*sc2+bt2, (dB[3]+cb2)*sc2+bt2), 0.f);
        const int rr[4] = { m0+2*g, m0+2*g+1, m0+8+2*g, m0+8+2*g+1 };
        #pragma unroll
        for (int i = 0; i < 4; ++i) {
          const float ang = (float)rr[i] * efac;
          const float pe = (d & 1) ? cosf(ang) : sinf(ang);
          *(_Float16*)swp(xs, rr[i], 128, d*2) = (_Float16)(v[i] + pe);
        }
      }
    }
  }
  __syncthreads();

  // ================= transformer layers =================
  for (int layer = 0; layer < 2; ++layer) {
    const int wi = s*2 + layer;
    const unsigned short* wq = w16 + (size_t)wi*49152;
    const unsigned short* wo = wq + 12288;
    const unsigned short* w1 = wq + 16384;
    const unsigned short* w2 = wq + 32768;
    const float* Bq  = bqkv + wi*192;
    const float* Bo  = bo   + wi*64;
    const float* G1  = ln1g + wi*64; const float* B1 = ln1b + wi*64;
    const float* Bf1 = fb1  + wi*256; const float* Bf2 = fb2 + wi*64;
    const float* G2  = ln2g + wi*64; const float* B2 = ln2b + wi*64;

    // ======== QKV projections ========
    {
      f16x8 xf0 = *(const f16x8*)swp(xs, m0+c, 128, 0  + g*16);
      f16x8 xf1 = *(const f16x8*)swp(xs, m0+c, 128, 64 + g*16);
      #pragma unroll
      for (int nt = 0; nt < 4; ++nt) {
        const int row = 64 + nt*16 + c;
        f16x8 w0f = *(const f16x8*)(wq + row*64 + 8*g);
        f16x8 w1f = *(const f16x8*)(wq + row*64 + 32 + 8*g);
        f32x4 d = {0.f,0.f,0.f,0.f};
        d = MFMA32(w0f, xf0, d); d = MFMA32(w1f, xf1, d);
        float4 b4 = *(const float4*)(Bq + 64 + nt*16 + 4*g);
        *(uint2*)swp(Kb, m0+c, 128, nt*32 + 8*g) =
            pack4u(d[0]+b4.x, d[1]+b4.y, d[2]+b4.z, d[3]+b4.w);
      }
      #pragma unroll
      for (int nt = 0; nt < 4; ++nt) {
        const int row = nt*16 + c;
        f16x8 w0f = *(const f16x8*)(wq + row*64 + 8*g);
        f16x8 w1f = *(const f16x8*)(wq + row*64 + 32 + 8*g);
        f32x4 d = {0.f,0.f,0.f,0.f};
        d = MFMA32(w0f, xf0, d); d = MFMA32(w1f, xf1, d);
        float4 b4 = *(const float4*)(Bq + nt*16 + 4*g);
        *(uint2*)swp(Qb, m0+c, 128, nt*32 + 8*g) =
            pack4u((d[0]+b4.x)*qs, (d[1]+b4.y)*qs, (d[2]+b4.z)*qs, (d[3]+b4.w)*qs);
      }
      #pragma unroll
      for (int nt = 0; nt < 4; ++nt) {
        const int row = 128 + nt*16 + c;
        f16x8 w0f = *(const f16x8*)(wq + row*64 + 8*g);
        f16x8 w1f = *(const f16x8*)(wq + row*64 + 32 + 8*g);
        f32x4 d = {0.f,0.f,0.f,0.f};
        d = MFMA32(xf0, w0f, d); d = MFMA32(xf1, w1f, d);
        const float bias = Bq[128 + nt*16 + c];
        *(uint2*)swp(Vt, nt*16+c, 512, 32*w + 8*g) =
            pack4u(d[0]+bias, d[1]+bias, d[2]+bias, d[3]+bias);
      }
    }
    __syncthreads();   // (a) Q/K/Vt visible to all

    // ======== attention (single head per task, even/odd accumulator split) ========
    #pragma unroll 2
    for (int task = 0; task < 8; ++task) {
      const int h = task;
      f16x4 qb = {0,0,0,0};
      if (g < 2) qb = *(const f16x4*)swp(Qb, m0+c, 128, 16*h + 8*g);
      f32x4 oA = {0.f,0.f,0.f,0.f}, oB = {0.f,0.f,0.f,0.f};
      #pragma unroll
      for (int jt = 0; jt < 16; ++jt) {
        f16x4 ka = *(const f16x4*)swp(Kb, jt*16+c, 128, (16*h + 8*g) & 127);
        f32x4 st = {0.f,0.f,0.f,0.f};
        st = MFMA16(ka, qb, st);
        uint2 pu = pack4u(fast_exp2(st[0]), fast_exp2(st[1]),
                          fast_exp2(st[2]), fast_exp2(st[3]));
        f16x4 pb = *(f16x4*)&pu;
        f16x4 va;
        if (c < 8) va = *(const f16x4*)swp(Vt, 8*h+c, 512, jt*32 + (g>>1)*16 + (g&1)*8);
        else { va[0]=(_Float16)1.f; va[1]=(_Float16)1.f; va[2]=(_Float16)1.f; va[3]=(_Float16)1.f; }
        if (jt & 1) oB = MFMA16(va, pb, oB);
        else        oA = MFMA16(va, pb, oA);
      }
      f32x4 o;
      o[0] = oA[0]+oB[0]; o[1] = oA[1]+oB[1]; o[2] = oA[2]+oB[2]; o[3] = oA[3]+oB[3];
      const float den = __shfl(o[0], 32 + c, 64);
      const float rinv = 1.0f / den;
      if (g < 2) {
        *(uint2*)swp(Qb, m0+c, 128, 16*h + 8*g) =
            pack4u(o[0]*rinv, o[1]*rinv, o[2]*rinv, o[3]*rinv);
      }
    }
    __syncthreads();   // (b) cross-wave reads complete

    // ======== O-projection + residual + LN1 ========
    {
      f16x8 ab0 = *(const f16x8*)swp(Qb, m0+c, 128, 0  + g*16);
      f16x8 ab1 = *(const f16x8*)swp(Qb, m0+c, 128, 64 + g*16);
      float vals[4][4];
      #pragma unroll
      for (int nt = 0; nt < 4; ++nt) {
        f16x8 w0f = *(const f16x8*)(wo + (nt*16+c)*64 + 8*g);
        f16x8 w1f = *(const f16x8*)(wo + (nt*16+c)*64 + 32 + 8*g);
        f32x4 d = {0.f,0.f,0.f,0.f};
        d = MFMA32(w0f, ab0, d); d = MFMA32(w1f, ab1, d);
        float4 b4 = *(const float4*)(Bo + nt*16 + 4*g);
        uint2 rr = *(uint2*)swp(xs, m0+c, 128, nt*32 + 8*g);
        float2 r0 = __half22float2(*(__half2*)&rr.x);
        float2 r1 = __half22float2(*(__half2*)&rr.y);
        vals[nt][0] = d[0] + b4.x + r0.x;
        vals[nt][1] = d[1] + b4.y + r0.y;
        vals[nt][2] = d[2] + b4.z + r1.x;
        vals[nt][3] = d[3] + b4.w + r1.y;
      }
      float p1 = 0.f, p2 = 0.f;
      #pragma unroll
      for (int nt = 0; nt < 4; ++nt)
        #pragma unroll
        for (int i = 0; i < 4; ++i) { p1 += vals[nt][i]; p2 = fmaf(vals[nt][i], vals[nt][i], p2); }
      p1 += __shfl_xor(p1, 16, 64); p1 += __shfl_xor(p1, 32, 64);
      p2 += __shfl_xor(p2, 16, 64); p2 += __shfl_xor(p2, 32, 64);
      const float mean = p1*(1.0f/64.0f);
      const float rstd = rsqrtf(p2*(1.0f/64.0f) - mean*mean + 1e-5f);
      #pragma unroll
      for (int nt = 0; nt < 4; ++nt) {
        float4 g4 = *(const float4*)(G1 + nt*16 + 4*g);
        float4 b4 = *(const float4*)(B1 + nt*16 + 4*g);
        *(uint2*)swp(xs, m0+c, 128, nt*32 + 8*g) =
            pack4u((vals[nt][0]-mean)*rstd*g4.x + b4.x,
                   (vals[nt][1]-mean)*rstd*g4.y + b4.y,
                   (vals[nt][2]-mean)*rstd*g4.z + b4.z,
                   (vals[nt][3]-mean)*rstd*g4.w + b4.w);
      }
    }

    // ======== FF fused ========
    {
      f16x8 xb0 = *(const f16x8*)swp(xs, m0+c, 128, 0  + g*16);
      f16x8 xb1 = *(const f16x8*)swp(xs, m0+c, 128, 64 + g*16);
      f32x4 o2[4];
      #pragma unroll
      for (int nt2 = 0; nt2 < 4; ++nt2) { o2[nt2][0]=0.f; o2[nt2][1]=0.f; o2[nt2][2]=0.f; o2[nt2][3]=0.f; }
      #pragma unroll
      for (int ht = 0; ht < 16; ++ht) {
        f16x8 w0f = *(const f16x8*)(w1 + (ht*16+c)*64 + 8*g);
        f16x8 w1f = *(const f16x8*)(w1 + (ht*16+c)*64 + 32 + 8*g);
        f32x4 d = {0.f,0.f,0.f,0.f};
        d = MFMA32(w0f, xb0, d); d = MFMA32(w1f, xb1, d);
        float4 bf4 = *(const float4*)(Bf1 + ht*16 + 4*g);
        float h0 = d[0] + bf4.x, h1 = d[1] + bf4.y, h2 = d[2] + bf4.z, h3 = d[3] + bf4.w;
        h0 = 0.5f*h0*(1.0f + erff(h0*0.70710678118654752f));
        h1 = 0.5f*h1*(1.0f + erff(h1*0.70710678118654752f));
        h2 = 0.5f*h2*(1.0f + erff(h2*0.70710678118654752f));
        h3 = 0.5f*h3*(1.0f + erff(h3*0.70710678118654752f));
        uint2 pu = pack4u(h0, h1, h2, h3);
        f16x4 pf = *(f16x4*)&pu;
        #pragma unroll
        for (int nt2 = 0; nt2 < 4; ++nt2) {
          f16x4 a2 = *(const f16x4*)(w2 + (nt2*16+c)*256 + ht*16 + 4*g);
          o2[nt2] = MFMA16(a2, pf, o2[nt2]);
        }
      }
      float vals[4][4];
      #pragma unroll
      for (int nt2 = 0; nt2 < 4; ++nt2) {
        float4 b4 = *(const float4*)(Bf2 + nt2*16 + 4*g);
        uint2 rr = *(uint2*)swp(xs, m0+c, 128, nt2*32 + 8*g);
        float2 r0 = __half22float2(*(__half2*)&rr.x);
        float2 r1 = __half22float2(*(__half2*)&rr.y);
        vals[nt2][0] = o2[nt2][0] + b4.x + r0.x;
        vals[nt2][1] = o2[nt2][1] + b4.y + r0.y;
        vals[nt2][2] = o2[nt2][2] + b4.z + r1.x;
        vals[nt2][3] = o2[nt2][3] + b4.w + r1.y;
      }
      float p1 = 0.f, p2 = 0.f;
      #pragma unroll
      for (int nt2 = 0; nt2 < 4; ++nt2)
        #pragma unroll
        for (int i = 0; i < 4; ++i) { p1 += vals[nt2][i]; p2 = fmaf(vals[nt2][i], vals[nt2][i], p2); }
      p1 += __shfl_xor(p1, 16, 64); p1 += __shfl_xor(p1, 32, 64);
      p2 += __shfl_xor(p2, 16, 64); p2 += __shfl_xor(p2, 32, 64);
      const float mean = p1*(1.0f/64.0f);
      const float rstd = rsqrtf(p2*(1.0f/64.0f) - mean*mean + 1e-5f);
      #pragma unroll
      for (int nt2 = 0; nt2 < 4; ++nt2) {
        float4 g4 = *(const float4*)(G2 + nt2*16 + 4*g);
        float4 b4 = *(const float4*)(B2 + nt2*16 + 4*g);
        *(uint2*)swp(xs, m0+c, 128, nt2*32 + 8*g) =
            pack4u((vals[nt2][0]-mean)*rstd*g4.x + b4.x,
                   (vals[nt2][1]-mean)*rstd*g4.y + b4.y,
                   (vals[nt2][2]-mean)*rstd*g4.z + b4.z,
                   (vals[nt2][3]-mean)*rstd*g4.w + b4.w);
      }
    }
  }

  // ---- mean over sequence -> nf ----
  __syncthreads();
  if (t < 256) {
    const int d = t & 63, qu = t >> 6;
    float sm = 0.f;
    for (int rr = qu*64; rr < qu*64 + 64; ++rr) sm += sr_h(xs, rr, 128, d);
    red[qu*64 + d] = sm;
  }
  __syncthreads();
  if (t < 64) {
    float sm = red[t] + red[64+t] + red[128+t] + red[192+t];
    nf[((size_t)b*4 + s)*64 + t] = sm * (1.0f/256.0f);
  }
}

// ------------------------- graph head kernel (unchanged) -------------------------
__global__ __launch_bounds__(128) void head_kernel(
  const float* __restrict__ nf,
  const float* __restrict__ ws_w, const float* __restrict__ ws_b,
  const float* __restrict__ b_s,  const float* __restrict__ lambda_init,
  const float* __restrict__ mc_w1, const float* __restrict__ mc_b1,
  const float* __restrict__ mc_w2, const float* __restrict__ mc_b2,
  const float* __restrict__ g1w, const float* __restrict__ g1b,
  const float* __restrict__ g2w, const float* __restrict__ g2b,
  const float* __restrict__ cw1, const float* __restrict__ cb1,
  const float* __restrict__ cw2, const float* __restrict__ cb2,
  float* __restrict__ out)
{
  const int b = blockIdx.x, t = threadIdx.x;
  __shared__ float nfb[256];
  __shared__ float meannf[64];
  __shared__ float fafb[8];
  __shared__ float z1[32];
  __shared__ float normM[16];
  __shared__ float rs[4];
  __shared__ float xw[512];
  __shared__ float hmat[512];
  __shared__ float hw[1024];
  __shared__ float gv[256];
  __shared__ float r1[128];

  for (int i = t; i < 256; i += 128) nfb[i] = nf[b*256 + i];
  __syncthreads();
  if (t < 8) {
    const int i = t & 3;
    const float* w = ws_w + (t >> 2)*64;
    float acc = 0.f;
    for (int c = 0; c < 64; ++c) acc = fmaf(nfb[i*64+c], w[c], acc);
    fafb[t] = acc;
  }
  if (t >= 64 && t < 128) {
    const int d = t - 64;
    meannf[d] = 0.25f*(nfb[d] + nfb[64+d] + nfb[128+d] + nfb[192+d]);
  }
  __syncthreads();
  if (t < 32) {
    float acc = mc_b1[t];
    const float* w = mc_w1 + t*64;
    for (int c = 0; c < 64; ++c) acc = fmaf(meannf[c], w[c], acc);
    z1[t] = fmaxf(acc, 0.f);
  }
  __syncthreads();
  if (t == 0) {
    float li = mc_b2[0];
    for (int k = 0; k < 32; ++k) li = fmaf(z1[k], mc_w2[k], li);
    const float lam = (1.0f/(1.0f + __expf(-li))) * lambda_init[0];
    const float AB[4][4] = {{1,1,0,0},{1,1,1,1},{0,1,1,1},{0,1,1,1}};
    const float add = ws_b[0] + b_s[0];
    float sM[4][4], deg[4];
    for (int i = 0; i < 4; ++i) {
      float d_ = 0.f;
      for (int j = 0; j < 4; ++j) {
        sM[i][j] = 1.0f/(1.0f + __expf(-(fafb[i] + fafb[4+j] + add)));
        d_ += sM[i][j];
      }
      deg[i] = d_;
    }
    float A[4][4], dinv[4];
    for (int i = 0; i < 4; ++i)
      for (int j = 0; j < 4; ++j) {
        const float a_ = sM[i][j] / (deg[j] + 1e-8f);
        const float sh = fmaxf(a_ * AB[i][j], 0.f);
        A[i][j] = lam*((i==j) ? 1.f : 0.f) + (1.0f - lam)*sh;
      }
    for (int j = 0; j < 4; ++j) {
      float d_ = 0.f;
      for (int i = 0; i < 4; ++i) d_ += A[i][j];
      dinv[j] = (d_ > 0.f) ? rsqrtf(d_) : 0.f;
    }
    for (int i = 0; i < 4; ++i) {
      float r_ = 0.f;
      for (int j = 0; j < 4; ++j) {
        const float n_ = dinv[i]*A[i][j]*dinv[j];
        normM[i*4+j] = n_;
        r_ += n_;
      }
      rs[i] = r_;
    }
  }
  __syncthreads();
  for (int idx = t; idx < 512; idx += 128) {
    const int i = idx >> 7, f = idx & 127;
    float acc = 0.f;
    for (int c = 0; c < 64; ++c) acc = fmaf(nfb[i*64+c], g1w[c*128 + f], acc);
    xw[idx] = acc;
  }
  __syncthreads();
  for (int idx = t; idx < 512; idx += 128) {
    const int j = idx >> 7, f = idx & 127;
    float acc = g1b[f];
    #pragma unroll
    for (int i = 0; i < 4; ++i) acc = fmaf(normM[i*4+j], xw[i*128+f], acc);
    hmat[j*128+f] = fmaxf(acc, 0.f);
  }
  __syncthreads();
  for (int idx = t; idx < 1024; idx += 128) {
    const int i = idx >> 8, f = idx & 255;
    float acc = 0.f;
    for (int c = 0; c < 128; ++c) acc = fmaf(hmat[i*128+c], g2w[c*256+f], acc);
    hw[idx] = acc;
  }
  __syncthreads();
  for (int f = t; f < 256; f += 128) {
    float acc = 0.f;
    #pragma unroll
    for (int i = 0; i < 4; ++i) acc = fmaf(rs[i], hw[i*256+f], acc);
    gv[f] = 0.25f*acc + g2b[f];
  }
  __syncthreads();
  if (t < 128) {
    float acc = cb1[t];
    for (int c = 0; c < 256; ++c) acc = fmaf(gv[c], cw1[c*128+t], acc);
    r1[t] = fmaxf(acc, 0.f);
  }
  __syncthreads();
  if (t < 5) {
    float acc = cb2[t];
    for (int k = 0; k < 128; ++k) acc = fmaf(r1[k], cw2[k*5 + t], acc);
    out[b*5 + t] = acc;
  }
}

// ------------------------- launch -------------------------
extern "C" void kernel_launch(void* const* d_in, const int* in_sizes, int n_in,
                              void* d_out, int out_size, void* d_ws, size_t ws_size,
                              hipStream_t stream) {
  (void)in_sizes; (void)n_in; (void)out_size; (void)ws_size;
  const float* sens   = (const float*)d_in[0];
  const float* c1w    = (const float*)d_in[1];
  const float* c1b    = (const float*)d_in[2];
  const float* bn1g   = (const float*)d_in[3];
  const float* bn1b   = (const float*)d_in[4];
  const float* c2w    = (const float*)d_in[5];
  const float* c2b    = (const float*)d_in[6];
  const float* bn2g   = (const float*)d_in[7];
  const float* bn2b   = (const float*)d_in[8];
  const float* wqkv   = (const float*)d_in[9];
  const float* bqkv   = (const float*)d_in[10];
  const float* wo     = (const float*)d_in[11];
  const float* bo     = (const float*)d_in[12];
  const float* ln1g   = (const float*)d_in[13];
  const float* ln1b   = (const float*)d_in[14];
  const float* fw1    = (const float*)d_in[15];
  const float* fb1    = (const float*)d_in[16];
  const float* fw2    = (const float*)d_in[17];
  const float* fb2    = (const float*)d_in[18];
  const float* ln2g   = (const float*)d_in[19];
  const float* ln2b   = (const float*)d_in[20];
  const float* ws_w   = (const float*)d_in[21];
  const float* ws_b   = (const float*)d_in[22];
  const float* b_s    = (const float*)d_in[23];
  const float* lam0   = (const float*)d_in[24];
  const float* mc_w1  = (const float*)d_in[25];
  const float* mc_b1  = (const float*)d_in[26];
  const float* mc_w2  = (const float*)d_in[27];
  const float* mc_b2  = (const float*)d_in[28];
  const float* g1w    = (const float*)d_in[29];
  const float* g1b    = (const float*)d_in[30];
  const float* g2w    = (const float*)d_in[31];
  const float* g2b    = (const float*)d_in[32];
  const float* cw1    = (const float*)d_in[33];
  const float* cb1    = (const float*)d_in[34];
  const float* cw2    = (const float*)d_in[35];
  const float* cb2    = (const float*)d_in[36];

  float*          nf  = (float*)d_ws;                                  // 64 KiB
  unsigned short* w16 = (unsigned short*)((char*)d_ws + 65536);        // 768 KiB

  wprep_kernel<<<64, 256, 0, stream>>>(wqkv, wo, fw1, fw2, w16);
  tx_kernel<<<NSENS*NB, 1024, 0, stream>>>(sens, c1w, c1b, bn1g, bn1b,
                                           c2w, c2b, bn2g, bn2b,
                                           nf, w16, bqkv, bo,
                                           ln1g, ln1b, fb1, fb2, ln2g, ln2b);
  head_kernel<<<NB, 128, 0, stream>>>(nf, ws_w, ws_b, b_s, lam0,
                                      mc_w1, mc_b1, mc_w2, mc_b2,
                                      g1w, g1b, g2w, g2b, cw1, cb1, cw2, cb2,
                                      (float*)d_out);
}

// Round 18
// 214.859 us; speedup vs baseline: 1.1850x; 1.0031x over previous
//
#include <hip/hip_runtime.h>
#include <hip/hip_fp16.h>

#define NSENS 4
#define NB    64
#define LIN   2048
#define C1N   32
#define LP1   512
#define C2N   64
#define SEQ   256
#define DM    64

typedef _Float16 f16x4 __attribute__((ext_vector_type(4)));
typedef _Float16 f16x8 __attribute__((ext_vector_type(8)));
typedef float    f32x4 __attribute__((ext_vector_type(4)));

#define MFMA16(A,B,C) __builtin_amdgcn_mfma_f32_16x16x16f16((A),(B),(C),0,0,0)
#define MFMA32(A,B,C) __builtin_amdgcn_mfma_f32_16x16x32_f16((A),(B),(C),0,0,0)

__device__ __forceinline__ float fast_exp2(float x) {
#if __has_builtin(__builtin_amdgcn_exp2f)
  return __builtin_amdgcn_exp2f(x);
#else
  return exp2f(x);
#endif
}

// swizzled LDS addressing: 16B-chunk XOR by (row&7)<<4
__device__ __forceinline__ char* swp(char* base, int row, int stride, int byteoff) {
  return base + row*stride + ((byteoff & ~15) ^ ((row & 7) << 4)) + (byteoff & 15);
}
__device__ __forceinline__ float sr_h(char* base, int row, int stride, int col) {
  return (float)*(const _Float16*)swp(base, row, stride, col*2);
}
__device__ __forceinline__ uint2 pack4u(float a, float b, float cc, float d) {
  __half2 h0 = __floats2half2_rn(a, b), h1 = __floats2half2_rn(cc, d);
  uint2 u; u.x = *(unsigned*)&h0; u.y = *(unsigned*)&h1; return u;
}

// ---------------- weight pack: fp32 -> fp16, 64 blocks ----------------
__global__ __launch_bounds__(256) void wprep_kernel(
    const float* __restrict__ wqkv, const float* __restrict__ wo,
    const float* __restrict__ fw1,  const float* __restrict__ fw2,
    unsigned short* __restrict__ w16)
{
  const int wi = blockIdx.x >> 3, chunk = blockIdx.x & 7;
  unsigned short* dst = w16 + (size_t)wi*49152;
  const float* s0 = wqkv + (size_t)wi*12288;
  const float* s1 = wo   + (size_t)wi*4096;
  const float* s2 = fw1  + (size_t)wi*16384;
  const float* s3 = fw2  + (size_t)wi*16384;
  const int lo = chunk*6144, hi = lo + 6144;
  for (int i = lo + threadIdx.x; i < hi; i += 256) {
    float v;
    if (i < 12288)      v = s0[i];
    else if (i < 16384) v = s1[i - 12288];
    else if (i < 32768) v = s2[i - 16384];
    else                v = s3[i - 32768];
    __half h = __float2half_rn(v);
    dst[i] = *(unsigned short*)&h;
  }
}

// ---------------- fused conv + transformer kernel: 1024 threads = 16 waves ----------------
// LDS map: xs[256][64]f16 @0 | Qb @32K | Kb @64K | Vt[64][256] @96K | red @128K
// conv prologue overlays: h1t[514][32]f16 @32768, w2hT[3][64][32]f16 @65664
__global__ __launch_bounds__(1024, 1) void tx_kernel(
  const float* __restrict__ sens,
  const float* __restrict__ c1w, const float* __restrict__ c1b,
  const float* __restrict__ bn1g, const float* __restrict__ bn1b,
  const float* __restrict__ c2w, const float* __restrict__ c2b,
  const float* __restrict__ bn2g, const float* __restrict__ bn2b,
  float* __restrict__ nf,
  const unsigned short* __restrict__ w16,
  const float* __restrict__ bqkv, const float* __restrict__ bo,
  const float* __restrict__ ln1g, const float* __restrict__ ln1b,
  const float* __restrict__ fb1,  const float* __restrict__ fb2,
  const float* __restrict__ ln2g, const float* __restrict__ ln2b)
{
  __shared__ char smem[132096];
  char* xs = smem;
  char* Qb = smem + 32768;
  char* Kb = smem + 65536;
  char* Vt = smem + 98304;
  float* red = (float*)(smem + 131072);

  const int bid = blockIdx.x;
  const int s = bid >> 6, b = bid & 63;
  const int t = threadIdx.x;
  const int l = t & 63, w = t >> 6;
  const int g = l >> 4, c = l & 15;
  const int m0 = w * 16;
  const float qs = 0.35355339059327373f * 1.4426950408889634f; // 1/sqrt(8)*log2(e)

  // ================= conv prologue (MFMA conv2) =================
  {
    __half* h1t  = (__half*)(smem + 32768);    // [514][32]
    __half* w2hT = (__half*)(smem + 65664);    // [3][64][32]

    for (int i = t; i < 3*64*32; i += 1024) {
      const int ci = i & 31; const int rem = i >> 5; const int co = rem & 63; const int k = rem >> 6;
      w2hT[i] = __float2half_rn(c2w[((s*C2N + co)*C1N + ci)*3 + k]);
    }
    if (t < 32) { h1t[t] = __float2half(0.f); h1t[513*32 + t] = __float2half(0.f); }

    const float* xg = sens + (size_t)(s*NB + b)*LIN;
    const float bnr = rsqrtf(1.0f + 1e-5f);
    {
      const int ch = t & 31;
      const int l0 = t >> 5;
      const float w0 = c1w[(s*C1N + ch)*5 + 0];
      const float w1 = c1w[(s*C1N + ch)*5 + 1];
      const float w2 = c1w[(s*C1N + ch)*5 + 2];
      const float w3 = c1w[(s*C1N + ch)*5 + 3];
      const float w4 = c1w[(s*C1N + ch)*5 + 4];
      const float cb = c1b[s*C1N + ch];
      const float sc = bn1g[s*C1N + ch]*bnr;
      const float bt = bn1b[s*C1N + ch];
      for (int ll = l0; ll < LP1; ll += 32) {
        const int base = 4*ll;
        float xm2 = (base-2 >= 0) ? xg[base-2] : 0.f;
        float xm1 = (base-1 >= 0) ? xg[base-1] : 0.f;
        float x0v = xg[base+0];
        float x1v = xg[base+1];
        float x2v = xg[base+2];
        float x3v = xg[base+3];
        float x4v = (base+4 < LIN) ? xg[base+4] : 0.f;
        float y0 = w0*xm2 + w1*xm1 + w2*x0v + w3*x1v + w4*x2v;
        float y1 = w0*x0v + w1*x1v + w2*x2v + w3*x3v + w4*x4v;
        y0 = (y0 + cb)*sc + bt;
        y1 = (y1 + cb)*sc + bt;
        h1t[(ll+1)*32 + ch] = __float2half(fmaxf(fmaxf(y0, y1), 0.f));
      }
    }
    __syncthreads();
    {
      const int p0a = m0*2, p0b = m0*2 + 16;
      f16x8 aA[3], aB[3];
      #pragma unroll
      for (int k = 0; k < 3; ++k) {
        aA[k] = *(const f16x8*)&h1t[(p0a + c + k)*32 + 8*g];
        aB[k] = *(const f16x8*)&h1t[(p0b + c + k)*32 + 8*g];
      }
      #pragma unroll
      for (int ct = 0; ct < 4; ++ct) {
        f32x4 dA = {0.f,0.f,0.f,0.f}, dB = {0.f,0.f,0.f,0.f};
        #pragma unroll
        for (int k = 0; k < 3; ++k) {
          f16x8 bw = *(const f16x8*)&w2hT[(k*64 + ct*16 + c)*32 + 8*g];
          dA = MFMA32(aA[k], bw, dA);
          dB = MFMA32(aB[k], bw, dB);
        }
        const int d = ct*16 + c;
        const float cb2 = c2b[s*C2N + d];
        const float sc2 = bn2g[s*C2N + d]*bnr;
        const float bt2 = bn2b[s*C2N + d];
        const float efac = __expf(-0.14391156463f*(float)(d & ~1));
        float v[4];
        v[0] = fmaxf(fmaxf((dA[0]+cb2)*sc2+bt2, (dA[1]+cb2)*sc2+bt2), 0.f);
        v[1] = fmaxf(fmaxf((dA[2]+cb2)*sc2+bt2, (dA[3]+cb2)*sc2+bt2), 0.f);
        v[2] = fmaxf(fmaxf((dB[0]+cb2)*sc2+bt2, (dB[1]+cb2)*sc2+bt2), 0.f);
        v[3] = fmaxf(fmaxf((dB[2]+cb2)*sc2+bt2, (dB[3]+cb2)*sc2+bt2), 0.f);
        const int rr[4] = { m0+2*g, m0+2*g+1, m0+8+2*g, m0+8+2*g+1 };
        #pragma unroll
        for (int i = 0; i < 4; ++i) {
          const float ang = (float)rr[i] * efac;
          const float pe = (d & 1) ? cosf(ang) : sinf(ang);
          *(_Float16*)swp(xs, rr[i], 128, d*2) = (_Float16)(v[i] + pe);
        }
      }
    }
  }
  __syncthreads();

  // ================= transformer layers =================
  for (int layer = 0; layer < 2; ++layer) {
    const int wi = s*2 + layer;
    const unsigned short* wq = w16 + (size_t)wi*49152;
    const unsigned short* wo = wq + 12288;
    const unsigned short* w1 = wq + 16384;
    const unsigned short* w2 = wq + 32768;
    const float* Bq  = bqkv + wi*192;
    const float* Bo  = bo   + wi*64;
    const float* G1  = ln1g + wi*64; const float* B1 = ln1b + wi*64;
    const float* Bf1 = fb1  + wi*256; const float* Bf2 = fb2 + wi*64;
    const float* G2  = ln2g + wi*64; const float* B2 = ln2b + wi*64;

    // ======== QKV projections ========
    {
      f16x8 xf0 = *(const f16x8*)swp(xs, m0+c, 128, 0  + g*16);
      f16x8 xf1 = *(const f16x8*)swp(xs, m0+c, 128, 64 + g*16);
      #pragma unroll
      for (int nt = 0; nt < 4; ++nt) {
        const int row = 64 + nt*16 + c;
        f16x8 w0f = *(const f16x8*)(wq + row*64 + 8*g);
        f16x8 w1f = *(const f16x8*)(wq + row*64 + 32 + 8*g);
        f32x4 d = {0.f,0.f,0.f,0.f};
        d = MFMA32(w0f, xf0, d); d = MFMA32(w1f, xf1, d);
        float4 b4 = *(const float4*)(Bq + 64 + nt*16 + 4*g);
        *(uint2*)swp(Kb, m0+c, 128, nt*32 + 8*g) =
            pack4u(d[0]+b4.x, d[1]+b4.y, d[2]+b4.z, d[3]+b4.w);
      }
      #pragma unroll
      for (int nt = 0; nt < 4; ++nt) {
        const int row = nt*16 + c;
        f16x8 w0f = *(const f16x8*)(wq + row*64 + 8*g);
        f16x8 w1f = *(const f16x8*)(wq + row*64 + 32 + 8*g);
        f32x4 d = {0.f,0.f,0.f,0.f};
        d = MFMA32(w0f, xf0, d); d = MFMA32(w1f, xf1, d);
        float4 b4 = *(const float4*)(Bq + nt*16 + 4*g);
        *(uint2*)swp(Qb, m0+c, 128, nt*32 + 8*g) =
            pack4u((d[0]+b4.x)*qs, (d[1]+b4.y)*qs, (d[2]+b4.z)*qs, (d[3]+b4.w)*qs);
      }
      #pragma unroll
      for (int nt = 0; nt < 4; ++nt) {
        const int row = 128 + nt*16 + c;
        f16x8 w0f = *(const f16x8*)(wq + row*64 + 8*g);
        f16x8 w1f = *(const f16x8*)(wq + row*64 + 32 + 8*g);
        f32x4 d = {0.f,0.f,0.f,0.f};
        d = MFMA32(xf0, w0f, d); d = MFMA32(xf1, w1f, d);
        const float bias = Bq[128 + nt*16 + c];
        *(uint2*)swp(Vt, nt*16+c, 512, 32*w + 8*g) =
            pack4u(d[0]+bias, d[1]+bias, d[2]+bias, d[3]+bias);
      }
    }
    __syncthreads();   // (a) Q/K/Vt visible to all

    // ======== attention (setprio around MFMAs; waves desync between barriers) ========
    #pragma unroll 2
    for (int task = 0; task < 8; ++task) {
      const int h = task;
      f16x4 qb = {0,0,0,0};
      if (g < 2) qb = *(const f16x4*)swp(Qb, m0+c, 128, 16*h + 8*g);
      f32x4 oA = {0.f,0.f,0.f,0.f}, oB = {0.f,0.f,0.f,0.f};
      #pragma unroll
      for (int jt = 0; jt < 16; ++jt) {
        f16x4 ka = *(const f16x4*)swp(Kb, jt*16+c, 128, (16*h + 8*g) & 127);
        f32x4 st = {0.f,0.f,0.f,0.f};
        __builtin_amdgcn_s_setprio(1);
        st = MFMA16(ka, qb, st);
        __builtin_amdgcn_s_setprio(0);
        uint2 pu = pack4u(fast_exp2(st[0]), fast_exp2(st[1]),
                          fast_exp2(st[2]), fast_exp2(st[3]));
        f16x4 pb = *(f16x4*)&pu;
        f16x4 va;
        if (c < 8) va = *(const f16x4*)swp(Vt, 8*h+c, 512, jt*32 + (g>>1)*16 + (g&1)*8);
        else { va[0]=(_Float16)1.f; va[1]=(_Float16)1.f; va[2]=(_Float16)1.f; va[3]=(_Float16)1.f; }
        __builtin_amdgcn_s_setprio(1);
        if (jt & 1) oB = MFMA16(va, pb, oB);
        else        oA = MFMA16(va, pb, oA);
        __builtin_amdgcn_s_setprio(0);
      }
      f32x4 o;
      o[0] = oA[0]+oB[0]; o[1] = oA[1]+oB[1]; o[2] = oA[2]+oB[2]; o[3] = oA[3]+oB[3];
      const float den = __shfl(o[0], 32 + c, 64);
      const float rinv = 1.0f / den;
      if (g < 2) {
        *(uint2*)swp(Qb, m0+c, 128, 16*h + 8*g) =
            pack4u(o[0]*rinv, o[1]*rinv, o[2]*rinv, o[3]*rinv);
      }
    }
    __syncthreads();   // (b) cross-wave reads complete

    // ======== O-projection + residual + LN1 ========
    {
      f16x8 ab0 = *(const f16x8*)swp(Qb, m0+c, 128, 0  + g*16);
      f16x8 ab1 = *(const f16x8*)swp(Qb, m0+c, 128, 64 + g*16);
      float vals[4][4];
      #pragma unroll
      for (int nt = 0; nt < 4; ++nt) {
        f16x8 w0f = *(const f16x8*)(wo + (nt*16+c)*64 + 8*g);
        f16x8 w1f = *(const f16x8*)(wo + (nt*16+c)*64 + 32 + 8*g);
        f32x4 d = {0.f,0.f,0.f,0.f};
        d = MFMA32(w0f, ab0, d); d = MFMA32(w1f, ab1, d);
        float4 b4 = *(const float4*)(Bo + nt*16 + 4*g);
        uint2 rr = *(uint2*)swp(xs, m0+c, 128, nt*32 + 8*g);
        float2 r0 = __half22float2(*(__half2*)&rr.x);
        float2 r1 = __half22float2(*(__half2*)&rr.y);
        vals[nt][0] = d[0] + b4.x + r0.x;
        vals[nt][1] = d[1] + b4.y + r0.y;
        vals[nt][2] = d[2] + b4.z + r1.x;
        vals[nt][3] = d[3] + b4.w + r1.y;
      }
      float p1 = 0.f, p2 = 0.f;
      #pragma unroll
      for (int nt = 0; nt < 4; ++nt)
        #pragma unroll
        for (int i = 0; i < 4; ++i) { p1 += vals[nt][i]; p2 = fmaf(vals[nt][i], vals[nt][i], p2); }
      p1 += __shfl_xor(p1, 16, 64); p1 += __shfl_xor(p1, 32, 64);
      p2 += __shfl_xor(p2, 16, 64); p2 += __shfl_xor(p2, 32, 64);
      const float mean = p1*(1.0f/64.0f);
      const float rstd = rsqrtf(p2*(1.0f/64.0f) - mean*mean + 1e-5f);
      #pragma unroll
      for (int nt = 0; nt < 4; ++nt) {
        float4 g4 = *(const float4*)(G1 + nt*16 + 4*g);
        float4 b4 = *(const float4*)(B1 + nt*16 + 4*g);
        *(uint2*)swp(xs, m0+c, 128, nt*32 + 8*g) =
            pack4u((vals[nt][0]-mean)*rstd*g4.x + b4.x,
                   (vals[nt][1]-mean)*rstd*g4.y + b4.y,
                   (vals[nt][2]-mean)*rstd*g4.z + b4.z,
                   (vals[nt][3]-mean)*rstd*g4.w + b4.w);
      }
    }

    // ======== FF fused ========
    {
      f16x8 xb0 = *(const f16x8*)swp(xs, m0+c, 128, 0  + g*16);
      f16x8 xb1 = *(const f16x8*)swp(xs, m0+c, 128, 64 + g*16);
      f32x4 o2[4];
      #pragma unroll
      for (int nt2 = 0; nt2 < 4; ++nt2) { o2[nt2][0]=0.f; o2[nt2][1]=0.f; o2[nt2][2]=0.f; o2[nt2][3]=0.f; }
      #pragma unroll
      for (int ht = 0; ht < 16; ++ht) {
        f16x8 w0f = *(const f16x8*)(w1 + (ht*16+c)*64 + 8*g);
        f16x8 w1f = *(const f16x8*)(w1 + (ht*16+c)*64 + 32 + 8*g);
        f32x4 d = {0.f,0.f,0.f,0.f};
        d = MFMA32(w0f, xb0, d); d = MFMA32(w1f, xb1, d);
        float4 bf4 = *(const float4*)(Bf1 + ht*16 + 4*g);
        float h0 = d[0] + bf4.x, h1 = d[1] + bf4.y, h2 = d[2] + bf4.z, h3 = d[3] + bf4.w;
        h0 = 0.5f*h0*(1.0f + erff(h0*0.70710678118654752f));
        h1 = 0.5f*h1*(1.0f + erff(h1*0.70710678118654752f));
        h2 = 0.5f*h2*(1.0f + erff(h2*0.70710678118654752f));
        h3 = 0.5f*h3*(1.0f + erff(h3*0.70710678118654752f));
        uint2 pu = pack4u(h0, h1, h2, h3);
        f16x4 pf = *(f16x4*)&pu;
        #pragma unroll
        for (int nt2 = 0; nt2 < 4; ++nt2) {
          f16x4 a2 = *(const f16x4*)(w2 + (nt2*16+c)*256 + ht*16 + 4*g);
          o2[nt2] = MFMA16(a2, pf, o2[nt2]);
        }
      }
      float vals[4][4];
      #pragma unroll
      for (int nt2 = 0; nt2 < 4; ++nt2) {
        float4 b4 = *(const float4*)(Bf2 + nt2*16 + 4*g);
        uint2 rr = *(uint2*)swp(xs, m0+c, 128, nt2*32 + 8*g);
        float2 r0 = __half22float2(*(__half2*)&rr.x);
        float2 r1 = __half22float2(*(__half2*)&rr.y);
        vals[nt2][0] = o2[nt2][0] + b4.x + r0.x;
        vals[nt2][1] = o2[nt2][1] + b4.y + r0.y;
        vals[nt2][2] = o2[nt2][2] + b4.z + r1.x;
        vals[nt2][3] = o2[nt2][3] + b4.w + r1.y;
      }
      float p1 = 0.f, p2 = 0.f;
      #pragma unroll
      for (int nt2 = 0; nt2 < 4; ++nt2)
        #pragma unroll
        for (int i = 0; i < 4; ++i) { p1 += vals[nt2][i]; p2 = fmaf(vals[nt2][i], vals[nt2][i], p2); }
      p1 += __shfl_xor(p1, 16, 64); p1 += __shfl_xor(p1, 32, 64);
      p2 += __shfl_xor(p2, 16, 64); p2 += __shfl_xor(p2, 32, 64);
      const float mean = p1*(1.0f/64.0f);
      const float rstd = rsqrtf(p2*(1.0f/64.0f) - mean*mean + 1e-5f);
      #pragma unroll
      for (int nt2 = 0; nt2 < 4; ++nt2) {
        float4 g4 = *(const float4*)(G2 + nt2*16 + 4*g);
        float4 b4 = *(const float4*)(B2 + nt2*16 + 4*g);
        *(uint2*)swp(xs, m0+c, 128, nt2*32 + 8*g) =
            pack4u((vals[nt2][0]-mean)*rstd*g4.x + b4.x,
                   (vals[nt2][1]-mean)*rstd*g4.y + b4.y,
                   (vals[nt2][2]-mean)*rstd*g4.z + b4.z,
                   (vals[nt2][3]-mean)*rstd*g4.w + b4.w);
      }
    }
  }

  // ---- mean over sequence -> nf ----
  __syncthreads();
  if (t < 256) {
    const int d = t & 63, qu = t >> 6;
    float sm = 0.f;
    for (int rr = qu*64; rr < qu*64 + 64; ++rr) sm += sr_h(xs, rr, 128, d);
    red[qu*64 + d] = sm;
  }
  __syncthreads();
  if (t < 64) {
    float sm = red[t] + red[64+t] + red[128+t] + red[192+t];
    nf[((size_t)b*4 + s)*64 + t] = sm * (1.0f/256.0f);
  }
}

// ------------------------- graph head kernel (unchanged) -------------------------
__global__ __launch_bounds__(128) void head_kernel(
  const float* __restrict__ nf,
  const float* __restrict__ ws_w, const float* __restrict__ ws_b,
  const float* __restrict__ b_s,  const float* __restrict__ lambda_init,
  const float* __restrict__ mc_w1, const float* __restrict__ mc_b1,
  const float* __restrict__ mc_w2, const float* __restrict__ mc_b2,
  const float* __restrict__ g1w, const float* __restrict__ g1b,
  const float* __restrict__ g2w, const float* __restrict__ g2b,
  const float* __restrict__ cw1, const float* __restrict__ cb1,
  const float* __restrict__ cw2, const float* __restrict__ cb2,
  float* __restrict__ out)
{
  const int b = blockIdx.x, t = threadIdx.x;
  __shared__ float nfb[256];
  __shared__ float meannf[64];
  __shared__ float fafb[8];
  __shared__ float z1[32];
  __shared__ float normM[16];
  __shared__ float rs[4];
  __shared__ float xw[512];
  __shared__ float hmat[512];
  __shared__ float hw[1024];
  __shared__ float gv[256];
  __shared__ float r1[128];

  for (int i = t; i < 256; i += 128) nfb[i] = nf[b*256 + i];
  __syncthreads();
  if (t < 8) {
    const int i = t & 3;
    const float* w = ws_w + (t >> 2)*64;
    float acc = 0.f;
    for (int c = 0; c < 64; ++c) acc = fmaf(nfb[i*64+c], w[c], acc);
    fafb[t] = acc;
  }
  if (t >= 64 && t < 128) {
    const int d = t - 64;
    meannf[d] = 0.25f*(nfb[d] + nfb[64+d] + nfb[128+d] + nfb[192+d]);
  }
  __syncthreads();
  if (t < 32) {
    float acc = mc_b1[t];
    const float* w = mc_w1 + t*64;
    for (int c = 0; c < 64; ++c) acc = fmaf(meannf[c], w[c], acc);
    z1[t] = fmaxf(acc, 0.f);
  }
  __syncthreads();
  if (t == 0) {
    float li = mc_b2[0];
    for (int k = 0; k < 32; ++k) li = fmaf(z1[k], mc_w2[k], li);
    const float lam = (1.0f/(1.0f + __expf(-li))) * lambda_init[0];
    const float AB[4][4] = {{1,1,0,0},{1,1,1,1},{0,1,1,1},{0,1,1,1}};
    const float add = ws_b[0] + b_s[0];
    float sM[4][4], deg[4];
    for (int i = 0; i < 4; ++i) {
      float d_ = 0.f;
      for (int j = 0; j < 4; ++j) {
        sM[i][j] = 1.0f/(1.0f + __expf(-(fafb[i] + fafb[4+j] + add)));
        d_ += sM[i][j];
      }
      deg[i] = d_;
    }
    float A[4][4], dinv[4];
    for (int i = 0; i < 4; ++i)
      for (int j = 0; j < 4; ++j) {
        const float a_ = sM[i][j] / (deg[j] + 1e-8f);
        const float sh = fmaxf(a_ * AB[i][j], 0.f);
        A[i][j] = lam*((i==j) ? 1.f : 0.f) + (1.0f - lam)*sh;
      }
    for (int j = 0; j < 4; ++j) {
      float d_ = 0.f;
      for (int i = 0; i < 4; ++i) d_ += A[i][j];
      dinv[j] = (d_ > 0.f) ? rsqrtf(d_) : 0.f;
    }
    for (int i = 0; i < 4; ++i) {
      float r_ = 0.f;
      for (int j = 0; j < 4; ++j) {
        const float n_ = dinv[i]*A[i][j]*dinv[j];
        normM[i*4+j] = n_;
        r_ += n_;
      }
      rs[i] = r_;
    }
  }
  __syncthreads();
  for (int idx = t; idx < 512; idx += 128) {
    const int i = idx >> 7, f = idx & 127;
    float acc = 0.f;
    for (int c = 0; c < 64; ++c) acc = fmaf(nfb[i*64+c], g1w[c*128 + f], acc);
    xw[idx] = acc;
  }
  __syncthreads();
  for (int idx = t; idx < 512; idx += 128) {
    const int j = idx >> 7, f = idx & 127;
    float acc = g1b[f];
    #pragma unroll
    for (int i = 0; i < 4; ++i) acc = fmaf(normM[i*4+j], xw[i*128+f], acc);
    hmat[j*128+f] = fmaxf(acc, 0.f);
  }
  __syncthreads();
  for (int idx = t; idx < 1024; idx += 128) {
    const int i = idx >> 8, f = idx & 255;
    float acc = 0.f;
    for (int c = 0; c < 128; ++c) acc = fmaf(hmat[i*128+c], g2w[c*256+f], acc);
    hw[idx] = acc;
  }
  __syncthreads();
  for (int f = t; f < 256; f += 128) {
    float acc = 0.f;
    #pragma unroll
    for (int i = 0; i < 4; ++i) acc = fmaf(rs[i], hw[i*256+f], acc);
    gv[f] = 0.25f*acc + g2b[f];
  }
  __syncthreads();
  if (t < 128) {
    float acc = cb1[t];
    for (int c = 0; c < 256; ++c) acc = fmaf(gv[c], cw1[c*128+t], acc);
    r1[t] = fmaxf(acc, 0.f);
  }
  __syncthreads();
  if (t < 5) {
    float acc = cb2[t];
    for (int k = 0; k < 128; ++k) acc = fmaf(r1[k], cw2[k*5 + t], acc);
    out[b*5 + t] = acc;
  }
}

// ------------------------- launch -------------------------
extern "C" void kernel_launch(void* const* d_in, const int* in_sizes, int n_in,
                              void* d_out, int out_size, void* d_ws, size_t ws_size,
                              hipStream_t stream) {
  (void)in_sizes; (void)n_in; (void)out_size; (void)ws_size;
  const float* sens   = (const float*)d_in[0];
  const float* c1w    = (const float*)d_in[1];
  const float* c1b    = (const float*)d_in[2];
  const float* bn1g   = (const float*)d_in[3];
  const float* bn1b   = (const float*)d_in[4];
  const float* c2w    = (const float*)d_in[5];
  const float* c2b    = (const float*)d_in[6];
  const float* bn2g   = (const float*)d_in[7];
  const float* bn2b   = (const float*)d_in[8];
  const float* wqkv   = (const float*)d_in[9];
  const float* bqkv   = (const float*)d_in[10];
  const float* wo     = (const float*)d_in[11];
  const float* bo     = (const float*)d_in[12];
  const float* ln1g   = (const float*)d_in[13];
  const float* ln1b   = (const float*)d_in[14];
  const float* fw1    = (const float*)d_in[15];
  const float* fb1    = (const float*)d_in[16];
  const float* fw2    = (const float*)d_in[17];
  const float* fb2    = (const float*)d_in[18];
  const float* ln2g   = (const float*)d_in[19];
  const float* ln2b   = (const float*)d_in[20];
  const float* ws_w   = (const float*)d_in[21];
  const float* ws_b   = (const float*)d_in[22];
  const float* b_s    = (const float*)d_in[23];
  const float* lam0   = (const float*)d_in[24];
  const float* mc_w1  = (const float*)d_in[25];
  const float* mc_b1  = (const float*)d_in[26];
  const float* mc_w2  = (const float*)d_in[27];
  const float* mc_b2  = (const float*)d_in[28];
  const float* g1w    = (const float*)d_in[29];
  const float* g1b    = (const float*)d_in[30];
  const float* g2w    = (const float*)d_in[31];
  const float* g2b    = (const float*)d_in[32];
  const float* cw1    = (const float*)d_in[33];
  const float* cb1    = (const float*)d_in[34];
  const float* cw2    = (const float*)d_in[35];
  const float* cb2    = (const float*)d_in[36];

  float*          nf  = (float*)d_ws;                                  // 64 KiB
  unsigned short* w16 = (unsigned short*)((char*)d_ws + 65536);        // 768 KiB

  wprep_kernel<<<64, 256, 0, stream>>>(wqkv, wo, fw1, fw2, w16);
  tx_kernel<<<NSENS*NB, 1024, 0, stream>>>(sens, c1w, c1b, bn1g, bn1b,
                                           c2w, c2b, bn2g, bn2b,
                                           nf, w16, bqkv, bo,
                                           ln1g, ln1b, fb1, fb2, ln2g, ln2b);
  head_kernel<<<NB, 128, 0, stream>>>(nf, ws_w, ws_b, b_s, lam0,
                                      mc_w1, mc_b1, mc_w2, mc_b2,
                                      g1w, g1b, g2w, g2b, cw1, cb1, cw2, cb2,
                                      (float*)d_out);
}